// Round 3
// baseline (1374.515 us; speedup 1.0000x reference)
//
#include <hip/hip_runtime.h>
#include <math.h>

// LaplacianLoss: out[b] = vertex_weight * ||L @ x[b]||_F * NV
// Round-3: single-barrier double-buffered K-loop + 1-tile-ahead register
// prefetch of L. Block = 16 rows x half of K (20 tiles of 256 cols).
// Lane: 4 rows x 4 cols (float4 L) x 24 n. Epilogue ONCE per block:
// LDS transpose (sum over lanes BEFORE squaring) -> atomicAdd into C,
// then lap_reduce squares + reduces + sqrt (validated in round 2).

#define NVERT 10000
#define TJ 256
#define TPJG 20          // tiles per j-group (j-half)
#define RPW 4            // rows per wave
#define RPB 16           // rows per block
#define NRG 625
#define GRID1 (NRG * 2)
#define GRID2 40

__global__ __launch_bounds__(256, 3) void lap_main(
    const float* __restrict__ x, const float* __restrict__ L,
    float* __restrict__ C) {
  // two 6144-float x-tile buffers (49152 B -> 3 blocks/CU); epilogue reuses [0..6399]
  __shared__ __align__(16) float smem[12288];

  const int tid  = threadIdx.x;
  const int lane = tid & 63;
  const int wave = tid >> 6;
  const int rg   = blockIdx.x >> 1;
  const int jg   = blockIdx.x & 1;
  const int row0 = rg * RPB + wave * RPW;
  const int t0   = jg * TPJG;
  const int b0   = 2 * wave;   // this wave stages batches b0, b0+1

  float acc[RPW][24];
#pragma unroll
  for (int r = 0; r < RPW; ++r)
#pragma unroll
    for (int n = 0; n < 24; ++n) acc[r][n] = 0.f;

  const float4* __restrict__ xg = (const float4*)x;  // [b][2500 f4]
  float4* const smem4 = (float4*)smem;

  const float* Lb[RPW];
#pragma unroll
  for (int r = 0; r < RPW; ++r) Lb[r] = L + (long)(row0 + r) * NVERT;

  // ---- prologue: stage tile t0 into buf0 (first tile always 256 cols) ----
#pragma unroll
  for (int bb = 0; bb < 2; ++bb) {
    const int b = b0 + bb;
#pragma unroll
    for (int r = 0; r < 3; ++r) {
      const int idx = r * 64 + lane;
      smem4[b * 192 + idx] = xg[b * 7500 + t0 * 192 + idx];
    }
  }
  // prefetch L(t0)
  __align__(16) float Lc[RPW][4];
  {
    const int c0 = t0 * TJ + 4 * lane;
#pragma unroll
    for (int r = 0; r < RPW; ++r) *(float4*)&Lc[r][0] = *(const float4*)(Lb[r] + c0);
  }
  __syncthreads();

  // ---- main loop: one barrier per tile ----
#pragma unroll 2
  for (int tt = 0; tt < TPJG; ++tt) {
    const int q = tt & 1;
    const int t = t0 + tt;
    const bool last = (tt == TPJG - 1);
    const int jc  = (jg == 1 && tt == TPJG - 1) ? 16 : TJ;  // current tile cols
    const int jcn = (jg == 1 && tt == TPJG - 2) ? 16 : TJ;  // next tile cols
    const int nf4 = (jcn * 3) >> 2;                          // 192 or 12

    // phase 1: issue next x-tile loads (L2-resident, ~250 cyc)
    float4 sv[2][3];
    if (!last) {
#pragma unroll
      for (int bb = 0; bb < 2; ++bb) {
        const int b = b0 + bb;
#pragma unroll
        for (int r = 0; r < 3; ++r) {
          const int idx = r * 64 + lane;
          if (idx < nf4) sv[bb][r] = xg[b * 7500 + (t + 1) * 192 + idx];
        }
      }
    }

    const bool act = (4 * lane < jc);
    const float* xs = smem + q * 6144 + 12 * lane;

    // phase 2: compute batches 0..3 on current buffer with prefetched Lc
    if (act) {
#pragma unroll
      for (int b = 0; b < 4; ++b) {
        __align__(16) float xv[12];
        *(float4*)&xv[0] = *(const float4*)(xs + b * 768);
        *(float4*)&xv[4] = *(const float4*)(xs + b * 768 + 4);
        *(float4*)&xv[8] = *(const float4*)(xs + b * 768 + 8);
#pragma unroll
        for (int r = 0; r < RPW; ++r)
#pragma unroll
          for (int jj = 0; jj < 4; ++jj)
#pragma unroll
            for (int k = 0; k < 3; ++k)
              acc[r][b * 3 + k] += Lc[r][jj] * xv[jj * 3 + k];
      }
    }

    // phase 3: write staged x into the OTHER buffer (loads arrived under phase 2)
    if (!last) {
#pragma unroll
      for (int bb = 0; bb < 2; ++bb) {
        const int b = b0 + bb;
#pragma unroll
        for (int r = 0; r < 3; ++r) {
          const int idx = r * 64 + lane;
          if (idx < nf4) smem4[(1 - q) * 1536 + b * 192 + idx] = sv[bb][r];
        }
      }
    }

    // phase 4: prefetch next L tile (HBM ~900 cyc; ~1800+ cyc of cover left)
    __align__(16) float Ln[RPW][4] = {};
    if (!last && 4 * lane < jcn) {
      const int cn = (t + 1) * TJ + 4 * lane;
#pragma unroll
      for (int r = 0; r < RPW; ++r) *(float4*)&Ln[r][0] = *(const float4*)(Lb[r] + cn);
    }

    // phase 5: compute batches 4..7
    if (act) {
#pragma unroll
      for (int b = 4; b < 8; ++b) {
        __align__(16) float xv[12];
        *(float4*)&xv[0] = *(const float4*)(xs + b * 768);
        *(float4*)&xv[4] = *(const float4*)(xs + b * 768 + 4);
        *(float4*)&xv[8] = *(const float4*)(xs + b * 768 + 8);
#pragma unroll
        for (int r = 0; r < RPW; ++r)
#pragma unroll
          for (int jj = 0; jj < 4; ++jj)
#pragma unroll
            for (int k = 0; k < 3; ++k)
              acc[r][b * 3 + k] += Lc[r][jj] * xv[jj * 3 + k];
      }
    }

    __syncthreads();  // next buffer staged + everyone done reading buf q
#pragma unroll
    for (int r = 0; r < RPW; ++r)
#pragma unroll
      for (int jj = 0; jj < 4; ++jj) Lc[r][jj] = Ln[r][jj];
  }

  // ---- epilogue (once per block): cross-lane sum per (row,n) -> atomics to C ----
  for (int w = 0; w < 4; ++w) {
    __syncthreads();
    if (wave == w) {
#pragma unroll
      for (int r = 0; r < RPW; ++r)
#pragma unroll
        for (int c = 0; c < 6; ++c)
          *(float4*)&smem[lane * 100 + r * 24 + c * 4] = *(float4*)&acc[r][c * 4];
    }
    __syncthreads();
    if (tid < 96) {
      float s = 0.f;
#pragma unroll
      for (int l = 0; l < 64; ++l) s += smem[l * 100 + tid];
      const int row = rg * RPB + w * RPW + tid / 24;
      atomicAdd(&C[row * 24 + (tid % 24)], s);
    }
  }
}

__global__ __launch_bounds__(256) void lap_reduce(
    const float* __restrict__ C, const float* __restrict__ wv,
    float* __restrict__ out, float* __restrict__ Sg, unsigned* __restrict__ ctr) {
  __shared__ float sS[8];
  const int tid = threadIdx.x;
  if (tid < 8) sS[tid] = 0.f;
  __syncthreads();

  const int row = blockIdx.x * 256 + tid;
  float pb[8] = {0.f, 0.f, 0.f, 0.f, 0.f, 0.f, 0.f, 0.f};
  if (row < NVERT) {
    const float* rp = C + (long)row * 24;
#pragma unroll
    for (int b = 0; b < 8; ++b) {
      float s = 0.f;
#pragma unroll
      for (int k = 0; k < 3; ++k) {
        float v = rp[b * 3 + k];
        s += v * v;
      }
      pb[b] = s;
    }
  }
#pragma unroll
  for (int b = 0; b < 8; ++b) atomicAdd(&sS[b], pb[b]);
  __syncthreads();
  if (tid < 8) atomicAdd(&Sg[tid], sS[tid]);
  __syncthreads();  // drains global atomics before the flag

  if (tid == 0) {
    __threadfence();
    unsigned old = atomicAdd(ctr, 1u);
    if (old == (unsigned)(gridDim.x - 1)) {
      __threadfence();
      const float w = wv[0];
#pragma unroll
      for (int b = 0; b < 8; ++b) {
        float s = atomicAdd(&Sg[b], 0.f);  // coherent read
        out[b] = w * sqrtf(s) * (float)NVERT;
      }
    }
  }
}

extern "C" void kernel_launch(void* const* d_in, const int* in_sizes, int n_in,
                              void* d_out, int out_size, void* d_ws, size_t ws_size,
                              hipStream_t stream) {
  const float* x  = (const float*)d_in[0];   // (8, 10000, 3) fp32
  const float* L  = (const float*)d_in[1];   // (10000, 10000) fp32
  const float* wv = (const float*)d_in[2];   // (1,) fp32
  float* out = (float*)d_out;                // (8,) fp32

  float* C      = (float*)d_ws;                       // 240000 floats
  float* Sg     = (float*)((char*)d_ws + 960000);     // 8 floats
  unsigned* ctr = (unsigned*)((char*)d_ws + 960032);  // counter

  hipMemsetAsync(d_ws, 0, 960064, stream);
  lap_main<<<GRID1, 256, 0, stream>>>(x, L, C);
  lap_reduce<<<GRID2, 256, 0, stream>>>(C, wv, out, Sg, ctr);
}

// Round 4
// 1166.287 us; speedup vs baseline: 1.1785x; 1.1785x over previous
//
#include <hip/hip_runtime.h>
#include <math.h>

// LaplacianLoss: out[b] = vertex_weight * ||L @ x[b]||_F * NV
// Round-4: round-3 pipeline (1 barrier/tile, dbuf x, 1-tile-ahead L prefetch)
// with the register pressure that caused round-3's scratch-spill catastrophe
// (VGPR_Count 84, 2.25 GB scratch writes) removed:
//  - x staged via global_load_lds width=16 (no staging VGPRs, no phase-3)
//  - L prefetch issued BEFORE compute (FMA+LDS covers the ~900cyc HBM latency)
//  - C split per j-half (plain stores, no zero-init, no memset, no atomics)
//  - lap_reduce: single block, shuffle-reduce, writes out directly.

#define NVERT 10000
#define TJ 256
#define TPJG 20          // tiles per j-half
#define RPW 4            // rows per wave
#define RPB 16           // rows per block
#define NRG 625
#define GRID1 (NRG * 2)

typedef const __attribute__((address_space(1))) void* as1_cptr;
typedef __attribute__((address_space(3))) void* as3_ptr;

__device__ __forceinline__ void lds_load16(void* lds, const void* g) {
  __builtin_amdgcn_global_load_lds((as1_cptr)g, (as3_ptr)lds, 16, 0, 0);
}

__global__ __launch_bounds__(256, 3) void lap_main(
    const float* __restrict__ x, const float* __restrict__ L,
    float* __restrict__ C) {
  // two x-tile buffers of 1536 float4 each (49152 B total -> 3 blocks/CU);
  // epilogue reuses floats [0..6399].
  __shared__ __align__(16) float smem[12288];

  const int tid  = threadIdx.x;
  const int lane = tid & 63;
  const int wave = tid >> 6;
  const int rg   = blockIdx.x >> 1;
  const int jg   = blockIdx.x & 1;
  const int row0 = rg * RPB + wave * RPW;
  const int t0   = jg * TPJG;
  const int b0   = 2 * wave;    // this wave stages batches b0, b0+1

  float acc[RPW][24];
#pragma unroll
  for (int r = 0; r < RPW; ++r)
#pragma unroll
    for (int n = 0; n < 24; ++n) acc[r][n] = 0.f;

  const float4* __restrict__ xg = (const float4*)x;  // [b][2500 f4]
  float4* const smem4 = (float4*)smem;
  const float* const Lbase = L + (long)row0 * NVERT;

  // ---- prologue: DMA-stage tile t0 into buf0; prefetch L(t0) ----
#pragma unroll
  for (int bb = 0; bb < 2; ++bb) {
    const int b = b0 + bb;
#pragma unroll
    for (int r = 0; r < 3; ++r) {
      const int idx = r * 64 + lane;
      const int gi = b * 7500 + t0 * 192 + idx;   // t0 tile is always full
      lds_load16(&smem4[b * 192 + idx], &xg[gi]);
    }
  }
  float4 Lc[RPW];
  {
    const int c0 = t0 * TJ + 4 * lane;
#pragma unroll
    for (int r = 0; r < RPW; ++r)
      Lc[r] = *(const float4*)(Lbase + r * NVERT + c0);
  }
  __syncthreads();  // drains the LDS-DMA (vmcnt) + all waves staged

  // ---- main loop: one barrier per tile ----
#pragma unroll 2
  for (int tt = 0; tt < TPJG; ++tt) {
    const int q = tt & 1;
    const int t = t0 + tt;
    const bool last = (tt == TPJG - 1);
    const int jc  = (jg == 1 && tt == TPJG - 1) ? 16 : TJ;  // this tile's cols
    const int jcn = (jg == 1 && tt == TPJG - 2) ? 16 : TJ;  // next tile's cols

    // phase A: DMA-stage next x tile into the other buffer (zero VGPR cost)
    if (!last) {
#pragma unroll
      for (int bb = 0; bb < 2; ++bb) {
        const int b = b0 + bb;
#pragma unroll
        for (int r = 0; r < 3; ++r) {
          const int idx = r * 64 + lane;
          int gi = (t + 1) * 192 + idx;
          gi = (gi < 7499 ? gi : 7499) + b * 7500;  // clamp: tail tile safety
          lds_load16(&smem4[(1 - q) * 1536 + b * 192 + idx], &xg[gi]);
        }
      }
    }

    // phase B: prefetch next L tile (HBM ~900cyc; covered by phase C)
    float4 Ln[RPW];
    if (!last && 4 * lane < jcn) {
      const int cn = (t + 1) * TJ + 4 * lane;
#pragma unroll
      for (int r = 0; r < RPW; ++r)
        Ln[r] = *(const float4*)(Lbase + r * NVERT + cn);
    }

    // phase C: compute all 8 batches on buffer q with prefetched Lc
    if (4 * lane < jc) {
      const float* xs = smem + q * 6144 + 12 * lane;
#pragma unroll
      for (int b = 0; b < 8; ++b) {
        __align__(16) float xv[12];
        *(float4*)&xv[0] = *(const float4*)(xs + b * 768);
        *(float4*)&xv[4] = *(const float4*)(xs + b * 768 + 4);
        *(float4*)&xv[8] = *(const float4*)(xs + b * 768 + 8);
        const float* Lp0 = (const float*)&Lc[0];
#pragma unroll
        for (int r = 0; r < RPW; ++r) {
          const float* Lp = (const float*)&Lc[r];
#pragma unroll
          for (int jj = 0; jj < 4; ++jj)
#pragma unroll
            for (int k = 0; k < 3; ++k)
              acc[r][b * 3 + k] += Lp[jj] * xv[jj * 3 + k];
        }
        (void)Lp0;
      }
    }

    __syncthreads();  // next buffer fully staged; buf q free for rewrite
#pragma unroll
    for (int r = 0; r < RPW; ++r) Lc[r] = Ln[r];
  }

  // ---- epilogue (once per block): cross-lane sum per (row,n) -> store C ----
  float* const Cs = C + jg * 240000;
  for (int w = 0; w < 4; ++w) {
    __syncthreads();
    if (wave == w) {
#pragma unroll
      for (int r = 0; r < RPW; ++r)
#pragma unroll
        for (int c = 0; c < 6; ++c)
          *(float4*)&smem[lane * 100 + r * 24 + c * 4] = *(float4*)&acc[r][c * 4];
    }
    __syncthreads();
    if (tid < 96) {
      float s = 0.f;
#pragma unroll
      for (int l = 0; l < 64; ++l) s += smem[l * 100 + tid];
      const int row = rg * RPB + w * RPW + tid / 24;
      Cs[row * 24 + (tid % 24)] = s;   // plain store: slice fully covered
    }
  }
}

__global__ __launch_bounds__(1024) void lap_reduce(
    const float* __restrict__ C, const float* __restrict__ wv,
    float* __restrict__ out) {
  __shared__ float sS[8];
  const int tid = threadIdx.x;
  if (tid < 8) sS[tid] = 0.f;
  __syncthreads();

  float pb[8] = {0.f, 0.f, 0.f, 0.f, 0.f, 0.f, 0.f, 0.f};
  for (int row = tid; row < NVERT; row += 1024) {
    const float4* r0 = (const float4*)(C + row * 24);
    const float4* r1 = (const float4*)(C + 240000 + row * 24);
    float v[24];
#pragma unroll
    for (int c = 0; c < 6; ++c) {
      float4 a = r0[c], b = r1[c];
      v[4 * c]     = a.x + b.x;
      v[4 * c + 1] = a.y + b.y;
      v[4 * c + 2] = a.z + b.z;
      v[4 * c + 3] = a.w + b.w;
    }
#pragma unroll
    for (int b = 0; b < 8; ++b)
#pragma unroll
      for (int k = 0; k < 3; ++k)
        pb[b] += v[b * 3 + k] * v[b * 3 + k];
  }
#pragma unroll
  for (int off = 32; off > 0; off >>= 1)
#pragma unroll
    for (int b = 0; b < 8; ++b) pb[b] += __shfl_down(pb[b], off);
  if ((tid & 63) == 0)
#pragma unroll
    for (int b = 0; b < 8; ++b) atomicAdd(&sS[b], pb[b]);
  __syncthreads();
  if (tid < 8) out[tid] = wv[0] * sqrtf(sS[tid]) * (float)NVERT;
}

extern "C" void kernel_launch(void* const* d_in, const int* in_sizes, int n_in,
                              void* d_out, int out_size, void* d_ws, size_t ws_size,
                              hipStream_t stream) {
  const float* x  = (const float*)d_in[0];   // (8, 10000, 3) fp32
  const float* L  = (const float*)d_in[1];   // (10000, 10000) fp32
  const float* wv = (const float*)d_in[2];   // (1,) fp32
  float* out = (float*)d_out;                // (8,) fp32

  float* C = (float*)d_ws;  // [2][10000][24] fp32, fully overwritten each call

  lap_main<<<GRID1, 256, 0, stream>>>(x, L, C);
  lap_reduce<<<1, 1024, 0, stream>>>(C, wv, out);
}